// Round 1
// baseline (184.604 us; speedup 1.0000x reference)
//
#include <hip/hip_runtime.h>

// L=8192, H=4096, B=2, N=2, E=2, FIRST_THRESHOLD=0.5
// out[l,0] = rr0 + rr2 * lin_n[l,0];  out[l,1] = rr1 + rr2 * lin_n[l,1]
// lin[l,e] = dot(x[l,:], W[e,:]) + b[e]; lin_n = lin / (lin0+lin1)
// hs = weights[l/4096, 0]
// hs>=0.5: rr=((hs-.5)*2, 0, (1-hs)*2); else rr=(0, (.5-hs)*2, hs*2).
//
// R4: kill the serial prologue. Previous version staged 32 KB of W into LDS
// behind a __syncthreads before any x load could issue, then paid ds_read +
// lgkmcnt in every inner iteration. Instead each wave owns a QUARTER of H
// (1024 cols) and keeps its W fragment in 32 VGPRs (8 x f32x4); it processes
// all 8 rows of the block over that quarter. Main loop = pure nontemporal
// load + FMA, no barrier, no LDS, no lgkmcnt. A 256 B LDS reduction at the
// end combines the four quarter-partials per row.

#define L_DIM 8192
#define H_DIM 4096

typedef float f32x4 __attribute__((ext_vector_type(4)));

__global__ __launch_bounds__(256, 4) void router_kernel(
    const float* __restrict__ x,        // (L, H)
    const float* __restrict__ weights,  // (2, 2)
    const float* __restrict__ W,        // (2, H)
    const float* __restrict__ b,        // (2,)
    float* __restrict__ out)            // (L, 2)
{
    __shared__ float sRed[4][8][2];     // [wave][row][e] quarter-partials

    const int wave = threadIdx.x >> 6;
    const int lane = threadIdx.x & 63;
    const int row_base = blockIdx.x * 8;          // 8 rows per block, grid = 1024

    // Wave w owns H-columns [w*1024, w*1024+1024) — 256 f32x4 per W row.
    const int qoff = wave * 256;                  // in f32x4 units
    const f32x4* w0q = (const f32x4*)W + qoff;
    const f32x4* w1q = (const f32x4*)(W + H_DIM) + qoff;

    // W fragment in registers: 8 x f32x4 = 32 VGPRs. Coalesced, L2-warm
    // after the first blocks; overlaps with the first x loads (no barrier).
    f32x4 wr0[4], wr1[4];
    #pragma unroll
    for (int j = 0; j < 4; ++j) {
        wr0[j] = w0q[j * 64 + lane];
        wr1[j] = w1q[j * 64 + lane];
    }

    float acc0[8], acc1[8];
    #pragma unroll
    for (int r = 0; r < 8; ++r) { acc0[r] = 0.f; acc1[r] = 0.f; }

    const f32x4* xbase = (const f32x4*)(x + (size_t)row_base * H_DIM) + qoff;

    // 32 nontemporal 16B loads per lane, fully unrolled; zero memory-order
    // dependencies in the loop body besides the loads themselves.
    #pragma unroll
    for (int r = 0; r < 8; ++r) {
        const f32x4* xr = xbase + (size_t)r * (H_DIM / 4);
        #pragma unroll
        for (int j = 0; j < 4; ++j) {
            const f32x4 xv = __builtin_nontemporal_load(&xr[j * 64 + lane]);
            acc0[r] += xv.x * wr0[j].x + xv.y * wr0[j].y + xv.z * wr0[j].z + xv.w * wr0[j].w;
            acc1[r] += xv.x * wr1[j].x + xv.y * wr1[j].y + xv.z * wr1[j].z + xv.w * wr1[j].w;
        }
    }

    // Wave-64 tree reduction of all 16 accumulators.
    #pragma unroll
    for (int off = 32; off > 0; off >>= 1) {
        #pragma unroll
        for (int r = 0; r < 8; ++r) {
            acc0[r] += __shfl_down(acc0[r], off, 64);
            acc1[r] += __shfl_down(acc1[r], off, 64);
        }
    }

    if (lane == 0) {
        #pragma unroll
        for (int r = 0; r < 8; ++r) {
            sRed[wave][r][0] = acc0[r];
            sRed[wave][r][1] = acc1[r];
        }
    }
    __syncthreads();

    // Threads 0..3 each finalize 2 adjacent rows -> one float4 store.
    if (threadIdx.x < 4) {
        const int r0 = threadIdx.x * 2;
        const float b0 = b[0], b1 = b[1];
        // All 8 rows of a block share the same weights row (block never
        // straddles the l=4096 boundary): row>>12 == blockIdx.x>>9.
        const float hs = weights[(blockIdx.x >> 9) * 2];
        float c0, c1, c2;
        if (hs >= 0.5f) { c0 = (hs - 0.5f) * 2.f; c1 = 0.f; c2 = (1.f - hs) * 2.f; }
        else            { c0 = 0.f; c1 = (0.5f - hs) * 2.f; c2 = hs * 2.f; }

        float4 o;
        {
            const float lin0 = sRed[0][r0][0] + sRed[1][r0][0] + sRed[2][r0][0] + sRed[3][r0][0] + b0;
            const float lin1 = sRed[0][r0][1] + sRed[1][r0][1] + sRed[2][r0][1] + sRed[3][r0][1] + b1;
            const float inv = 1.0f / (lin0 + lin1);
            o.x = c0 + c2 * (lin0 * inv);
            o.y = c1 + c2 * (lin1 * inv);
        }
        {
            const int r1 = r0 + 1;
            const float lin0 = sRed[0][r1][0] + sRed[1][r1][0] + sRed[2][r1][0] + sRed[3][r1][0] + b0;
            const float lin1 = sRed[0][r1][1] + sRed[1][r1][1] + sRed[2][r1][1] + sRed[3][r1][1] + b1;
            const float inv = 1.0f / (lin0 + lin1);
            o.z = c0 + c2 * (lin0 * inv);
            o.w = c1 + c2 * (lin1 * inv);
        }
        *(float4*)(out + (size_t)(row_base + r0) * 2) = o;
    }
}

extern "C" void kernel_launch(void* const* d_in, const int* in_sizes, int n_in,
                              void* d_out, int out_size, void* d_ws, size_t ws_size,
                              hipStream_t stream) {
    const float* x       = (const float*)d_in[0];   // (8192, 4096)
    const float* weights = (const float*)d_in[1];   // (2, 2)
    const float* W       = (const float*)d_in[2];   // (2, 4096)
    const float* b       = (const float*)d_in[3];   // (2,)
    float* out           = (float*)d_out;           // (8192, 2)

    router_kernel<<<L_DIM / 8, 256, 0, stream>>>(x, weights, W, b, out);
}